// Round 1
// baseline (69.855 us; speedup 1.0000x reference)
//
#include <hip/hip_runtime.h>
#include <math.h>

#define BB 4
#define SS 4096
#define HH 2048

// ---------------- Kernel 1: trigger-decay mask ----------------
// m[t] = max(hit[t], m[t-1]*0.95)  with hit in {0,1}
//      = 0.95^(t - last_hit_idx) if any hit at j<=t, else 0.
// One wave per batch row. Lane l owns contiguous segment [l*64, l*64+64).
__global__ __launch_bounds__(64) void trig_kernel(const int* __restrict__ ids,
                                                  float* __restrict__ trig) {
    __shared__ int sh[SS];
    const int b = blockIdx.x;
    const int lane = threadIdx.x;
    const int* row = ids + (size_t)b * SS;

    // coalesced stage to LDS
    for (int i = lane; i < SS; i += 64) sh[i] = row[i];
    __syncthreads();

    const int base = lane * 64;

    // pass 1: last hit index within my segment (-1 if none)
    int last = -1;
    #pragma unroll
    for (int k = 0; k < 64; ++k) {
        int v = sh[base + k];
        bool hit = (v == 5) || (v == 13) || (v == 42) || (v == 99);
        if (hit) last = base + k;
    }

    // wave inclusive max-scan of last-hit index
    int x = last;
    #pragma unroll
    for (int d = 1; d < 64; d <<= 1) {
        int y = __shfl_up(x, d);
        if (lane >= d) x = max(x, y);
    }
    int prev = __shfl_up(x, 1);
    int run = (lane == 0) ? -1 : prev;   // exclusive carry into my segment

    // pass 2: emit decay values
    const float LOG2_DECAY = -0.07400058144377693f;  // log2(0.95)
    float* orow = trig + (size_t)b * SS;
    #pragma unroll
    for (int k = 0; k < 64; ++k) {
        int s = base + k;
        int v = sh[s];
        bool hit = (v == 5) || (v == 13) || (v == 42) || (v == 99);
        if (hit) run = s;
        float m = (run < 0) ? 0.0f : exp2f((float)(s - run) * LOG2_DECAY);
        orow[s] = m;
    }
}

// ---------------- Kernel 2: fused norm + mask + scale ----------------
// One block (256 threads) per (b,s) row of H=2048 floats. Each thread holds
// 8 floats (2x float4) in registers; block-reduce sum of squares; then
// mask = 1 - max(trigger, payload)*w; write scaled row + mask scalar.
__global__ __launch_bounds__(256) void inhib_kernel(const float* __restrict__ h,
                                                    const float* __restrict__ trig,
                                                    const float* __restrict__ w,
                                                    float* __restrict__ out_h,
                                                    float* __restrict__ out_m) {
    const int row = blockIdx.x;
    const size_t off = (size_t)row * HH;
    const float4* hp = (const float4*)(h + off);
    const int t = threadIdx.x;

    float4 a = hp[t];
    float4 b4 = hp[t + 256];

    float ss = a.x * a.x + a.y * a.y + a.z * a.z + a.w * a.w
             + b4.x * b4.x + b4.y * b4.y + b4.z * b4.z + b4.w * b4.w;

    // wave reduce (64 lanes)
    #pragma unroll
    for (int d = 32; d > 0; d >>= 1) ss += __shfl_down(ss, d);

    __shared__ float sred[4];
    const int lane = t & 63, wid = t >> 6;
    if (lane == 0) sred[wid] = ss;
    __syncthreads();
    float total = sred[0] + sred[1] + sred[2] + sred[3];

    float norm = sqrtf(total);
    float dn = fmaxf(norm, 1e-12f);
    float sim = total / (dn * dn);
    sim = fminf(fmaxf(sim, 0.0f), 1.0f);
    float payload = ((1.0f - sim) > 0.5f) ? 1.0f : 0.0f;
    float combined = fmaxf(trig[row], payload);
    float maskv = 1.0f - combined * w[0];

    float4 oa = make_float4(a.x * maskv, a.y * maskv, a.z * maskv, a.w * maskv);
    float4 ob = make_float4(b4.x * maskv, b4.y * maskv, b4.z * maskv, b4.w * maskv);
    float4* op = (float4*)(out_h + off);
    op[t] = oa;
    op[t + 256] = ob;
    if (t == 0) out_m[row] = maskv;
}

extern "C" void kernel_launch(void* const* d_in, const int* in_sizes, int n_in,
                              void* d_out, int out_size, void* d_ws, size_t ws_size,
                              hipStream_t stream) {
    const float* hidden = (const float*)d_in[0];
    const int* ids = (const int*)d_in[1];
    const float* w = (const float*)d_in[2];

    float* out_h = (float*)d_out;                       // B*S*H floats
    float* out_m = out_h + (size_t)BB * SS * HH;        // B*S floats
    float* trig = (float*)d_ws;                         // B*S floats scratch

    trig_kernel<<<BB, 64, 0, stream>>>(ids, trig);
    inhib_kernel<<<BB * SS, 256, 0, stream>>>(hidden, trig, w, out_h, out_m);
}

// Round 2
// 48.845 us; speedup vs baseline: 1.4301x; 1.4301x over previous
//
#include <hip/hip_runtime.h>
#include <math.h>

#define BB 4
#define SS 4096
#define HH 2048

__device__ __forceinline__ bool is_hit(int v) {
    return (v == 5) || (v == 13) || (v == 42) || (v == 99);
}

// ---------------- Kernel 1: trigger-decay mask ----------------
// m[t] = max(hit[t], m[t-1]*0.95), hit in {0,1}
//      = 0.95^(t - last_hit_idx<=t) if any hit, else 0.
// One block (1024 threads = 16 waves) per batch row; 4 elems/thread.
__global__ __launch_bounds__(1024) void trig_kernel(const int* __restrict__ ids,
                                                    float* __restrict__ trig) {
    const int b = blockIdx.x;
    const int t = threadIdx.x;
    const int lane = t & 63, wid = t >> 6;
    const int base = t * 4;

    const int4 v = ((const int4*)(ids + (size_t)b * SS))[t];

    // last hit index within my 4 elements (-1 if none)
    int last = -1;
    if (is_hit(v.x)) last = base;
    if (is_hit(v.y)) last = base + 1;
    if (is_hit(v.z)) last = base + 2;
    if (is_hit(v.w)) last = base + 3;

    // wave inclusive max-scan
    int x = last;
    #pragma unroll
    for (int d = 1; d < 64; d <<= 1) {
        int y = __shfl_up(x, d);
        if (lane >= d) x = max(x, y);
    }

    // cross-wave exclusive carry
    __shared__ int wlast[16];
    if (lane == 63) wlast[wid] = x;
    __syncthreads();
    int carry = -1;
    for (int i = 0; i < wid; ++i) carry = max(carry, wlast[i]);  // LDS broadcast, <=15 iters

    int prev = __shfl_up(x, 1);
    int run = max(carry, (lane == 0) ? -1 : prev);  // exclusive prefix into my segment

    // emit decay values for my 4 elements
    const float LOG2_DECAY = -0.07400058144377693f;  // log2(0.95)
    float4 o;
    if (is_hit(v.x)) run = base;
    o.x = (run < 0) ? 0.0f : exp2f((float)(base - run) * LOG2_DECAY);
    if (is_hit(v.y)) run = base + 1;
    o.y = (run < 0) ? 0.0f : exp2f((float)(base + 1 - run) * LOG2_DECAY);
    if (is_hit(v.z)) run = base + 2;
    o.z = (run < 0) ? 0.0f : exp2f((float)(base + 2 - run) * LOG2_DECAY);
    if (is_hit(v.w)) run = base + 3;
    o.w = (run < 0) ? 0.0f : exp2f((float)(base + 3 - run) * LOG2_DECAY);

    ((float4*)(trig + (size_t)b * SS))[t] = o;
}

// ---------------- Kernel 2: fused norm + mask + scale ----------------
__global__ __launch_bounds__(256) void inhib_kernel(const float* __restrict__ h,
                                                    const float* __restrict__ trig,
                                                    const float* __restrict__ w,
                                                    float* __restrict__ out_h,
                                                    float* __restrict__ out_m) {
    const int row = blockIdx.x;
    const size_t off = (size_t)row * HH;
    const float4* hp = (const float4*)(h + off);
    const int t = threadIdx.x;

    float4 a = hp[t];
    float4 b4 = hp[t + 256];

    float ss = a.x * a.x + a.y * a.y + a.z * a.z + a.w * a.w
             + b4.x * b4.x + b4.y * b4.y + b4.z * b4.z + b4.w * b4.w;

    #pragma unroll
    for (int d = 32; d > 0; d >>= 1) ss += __shfl_down(ss, d);

    __shared__ float sred[4];
    const int lane = t & 63, wid = t >> 6;
    if (lane == 0) sred[wid] = ss;
    __syncthreads();
    float total = sred[0] + sred[1] + sred[2] + sred[3];

    float norm = sqrtf(total);
    float dn = fmaxf(norm, 1e-12f);
    float sim = total / (dn * dn);
    sim = fminf(fmaxf(sim, 0.0f), 1.0f);
    float payload = ((1.0f - sim) > 0.5f) ? 1.0f : 0.0f;
    float combined = fmaxf(trig[row], payload);
    float maskv = 1.0f - combined * w[0];

    float4 oa = make_float4(a.x * maskv, a.y * maskv, a.z * maskv, a.w * maskv);
    float4 ob = make_float4(b4.x * maskv, b4.y * maskv, b4.z * maskv, b4.w * maskv);
    float4* op = (float4*)(out_h + off);
    op[t] = oa;
    op[t + 256] = ob;
    if (t == 0) out_m[row] = maskv;
}

extern "C" void kernel_launch(void* const* d_in, const int* in_sizes, int n_in,
                              void* d_out, int out_size, void* d_ws, size_t ws_size,
                              hipStream_t stream) {
    const float* hidden = (const float*)d_in[0];
    const int* ids = (const int*)d_in[1];
    const float* w = (const float*)d_in[2];

    float* out_h = (float*)d_out;                    // B*S*H floats
    float* out_m = out_h + (size_t)BB * SS * HH;     // B*S floats
    float* trig = (float*)d_ws;                      // B*S floats scratch

    trig_kernel<<<BB, 1024, 0, stream>>>(ids, trig);
    inhib_kernel<<<BB * SS, 256, 0, stream>>>(hidden, trig, w, out_h, out_m);
}